// Round 13
// baseline (158.287 us; speedup 1.0000x reference)
//
#include <hip/hip_runtime.h>

// Round 13: 32x32 swapped-QK register-resident flash attention.
// Lane (q=l31, h=l5) holds 16/32 key-scores for ONE q -> softmax = in-reg tree
// + 1 shfl_xor(32). 32-key tiles amortize fixed costs. K,V: L2->reg fragments,
// phase-split prefetch, no main-loop barriers. Mask = precomputed f32 bias.
// Block 256 = 4 waves (1/SIMD, 512-reg budget) = 2 qw(32q) x 2 g(2048 keys).
//   d_in: 0=x f32, 1=mask i32, 2=Wk, 3=Wq, 4=Wv
// ws (f16): qT [BT/32][8192] | kT [BT/32][8192] | vT [BT/32][8192] | maskf f32[BT]
//   qT/kT tile: [s(16)][h(2)][row(32)][j(8)]  <-> X[row][s*16+h*8+j]  (q x1/16)
//   vT tile:    [dt(8)][ks(2)][h(2)][d(32)][j(8)] <-> V^T[dt*32+d][ks*16+h*8+j]

typedef __attribute__((ext_vector_type(8)))  _Float16 f16x8;
typedef __attribute__((ext_vector_type(4)))  _Float16 f16x4;
typedef __attribute__((ext_vector_type(4)))  float    f32x4;
typedef __attribute__((ext_vector_type(16))) float    f32x16;

constexpr int Bb = 4;
constexpr int Tt = 4096;
constexpr int Cc = 256;
constexpr int BT = Bb * Tt;
constexpr int NT = 64;                 // 32-key tiles per wave (64 x 32 = 2048 keys)

#define MFMA16(a, b, c) __builtin_amdgcn_mfma_f32_16x16x32_f16((a), (b), (c), 0, 0, 0)
#define MFMA32(a, b, c) __builtin_amdgcn_mfma_f32_32x32x16_f16((a), (b), (c), 0, 0, 0)

// ---------------- mask -> float bias ----------------
__global__ __launch_bounds__(256) void mask_prep(const int* __restrict__ m,
                                                 float* __restrict__ mf) {
    int i = blockIdx.x * 256 + threadIdx.x;
    mf[i] = (m[i] == 0) ? -1e30f : 0.0f;
}

// ---------------- Kernel A: fused QKV projection, 32x32-fragment layouts -----
__global__ __launch_bounds__(256) void qkv_proj(
    const float* __restrict__ x,
    const float* __restrict__ Wq, const float* __restrict__ Wk,
    const float* __restrict__ Wv,
    _Float16* __restrict__ qo, _Float16* __restrict__ ko,
    _Float16* __restrict__ vto)
{
    extern __shared__ _Float16 sm[];
    _Float16* xs = sm;              // [128][264]
    _Float16* wsm = sm + 128 * 264; // [128][264]

    const int tid = threadIdx.x;
    const int m0  = blockIdx.x * 128;
    const int ny  = blockIdx.y;
    const int mat = ny >> 1;              // 0=q 1=k 2=v
    const int d0  = (ny & 1) * 128;
    const float* W = (mat == 0) ? Wq : (mat == 1 ? Wk : Wv);

#pragma unroll
    for (int i = 0; i < 32; ++i) {
        int flat = i * 256 + tid;
        int r = flat >> 6, c4 = (flat & 63) << 2;
        float4 v = *reinterpret_cast<const float4*>(x + (size_t)(m0 + r) * Cc + c4);
        f16x4 h = { (_Float16)v.x, (_Float16)v.y, (_Float16)v.z, (_Float16)v.w };
        *reinterpret_cast<f16x4*>(xs + r * 264 + c4) = h;
    }
#pragma unroll
    for (int i = 0; i < 32; ++i) {
        int flat = i * 256 + tid;
        int r = flat >> 6, c4 = (flat & 63) << 2;
        float4 v = *reinterpret_cast<const float4*>(W + (size_t)(d0 + r) * Cc + c4);
        f16x4 h = { (_Float16)v.x, (_Float16)v.y, (_Float16)v.z, (_Float16)v.w };
        *reinterpret_cast<f16x4*>(wsm + r * 264 + c4) = h;
    }
    __syncthreads();

    const int w = tid >> 6, lane = tid & 63;
    const int lr = lane & 15, lg = lane >> 4;

    f32x4 acc[2][8] = {};

#pragma unroll
    for (int kc = 0; kc < 8; ++kc) {
        const int c0 = kc * 32 + lg * 8;
        f16x8 xf[2], wf[8];
#pragma unroll
        for (int mb = 0; mb < 2; ++mb)
            xf[mb] = *reinterpret_cast<const f16x8*>(xs + (w * 32 + mb * 16 + lr) * 264 + c0);
#pragma unroll
        for (int db = 0; db < 8; ++db)
            wf[db] = *reinterpret_cast<const f16x8*>(wsm + (db * 16 + lr) * 264 + c0);
        if (mat != 2) {
#pragma unroll
            for (int mb = 0; mb < 2; ++mb)
#pragma unroll
                for (int db = 0; db < 8; ++db)
                    acc[mb][db] = MFMA16(wf[db], xf[mb], acc[mb][db]);   // D[c][tok]
        } else {
#pragma unroll
            for (int mb = 0; mb < 2; ++mb)
#pragma unroll
                for (int db = 0; db < 8; ++db)
                    acc[mb][db] = MFMA16(xf[mb], wf[db], acc[mb][db]);   // D[tok][d]
        }
    }

    if (mat != 2) {
        // lane: token m (col=lr), c..c+3 (row=lg*4+reg): tile32 [s][h][row][j]
        const float sc = (mat == 0) ? 0.0625f : 1.0f;
        _Float16* dst = (mat == 0) ? qo : ko;
#pragma unroll
        for (int mb = 0; mb < 2; ++mb)
#pragma unroll
            for (int db = 0; db < 8; ++db) {
                int m  = m0 + w * 32 + mb * 16 + lr;
                int c  = d0 + db * 16 + lg * 4;
                int s  = c >> 4, h2 = (c >> 3) & 1, j0 = c & 7;
                f32x4 a = acc[mb][db];
                f16x4 h = { (_Float16)(a.x * sc), (_Float16)(a.y * sc),
                            (_Float16)(a.z * sc), (_Float16)(a.w * sc) };
                size_t off = (size_t)(m >> 5) * 8192 + s * 512 + h2 * 256
                           + (m & 31) * 8 + j0;
                *reinterpret_cast<f16x4*>(dst + off) = h;
            }
    } else {
        // lane: d (col=lr), keys m..m+3 (row): vT tile [dt][ks][h][d][j]
#pragma unroll
        for (int mb = 0; mb < 2; ++mb)
#pragma unroll
            for (int db = 0; db < 8; ++db) {
                int d = d0 + db * 16 + lr;
                int m = m0 + w * 32 + mb * 16 + lg * 4;
                f32x4 a = acc[mb][db];
                f16x4 h = { (_Float16)a.x, (_Float16)a.y, (_Float16)a.z, (_Float16)a.w };
                size_t off = (size_t)(m >> 5) * 8192 + (size_t)(d >> 5) * 1024
                           + ((m >> 4) & 1) * 512 + ((m >> 3) & 1) * 256
                           + (d & 31) * 8 + (m & 7);
                *reinterpret_cast<f16x4*>(vto + off) = h;
            }
    }
}

// ---------------- Kernel B: 32x32 swapped-QK flash attention ----------------
// LDS (bytes): [0,512) mex f32[4][32] | [512,1024) lex | [1024,10240) pw [4][32][36] f16
//              [10240,76288) oex f32[2 qw][32 q][258]
__global__ __launch_bounds__(256, 1) void attn_kernel(
    const _Float16* __restrict__ qb, const _Float16* __restrict__ kb,
    const _Float16* __restrict__ vtb, const float* __restrict__ maskf,
    float* __restrict__ outp)
{
    extern __shared__ char smraw[];
    float* mex  = (float*)(smraw);
    float* lex  = (float*)(smraw + 512);
    float* oexf = (float*)(smraw + 10240);

    const int tid = threadIdx.x, w = tid >> 6, lane = tid & 63;
    const int qw = w >> 1, g = w & 1;
    const int l31 = lane & 31, h = lane >> 5;

    const int bid = blockIdx.x;
    const int b   = (bid & 7) >> 1;                    // batch -> XCD pair
    const int qt  = ((bid >> 3) << 1) | (bid & 1);     // [0,64)
    const int q0  = qt * 64;
    const size_t base = (size_t)b * Tt * Cc;
    const _Float16* kTb = kb + base;
    const _Float16* vTb = vtb + base;
    const float* mfb = maskf + (size_t)b * Tt;

    // Q fragments (B-operand): Q[q = l31][c = s*16 + h*8 + j]
    f16x8 qf[16];
    {
        const _Float16* qTb = qb + (size_t)(b * 128 + qt * 2 + qw) * 8192
                            + h * 256 + l31 * 8;
#pragma unroll
        for (int s = 0; s < 16; ++s)
            qf[s] = *reinterpret_cast<const f16x8*>(qTb + s * 512);
    }

    _Float16* pw = (_Float16*)(smraw + 1024) + w * (32 * 36);

    f32x16 o[8] = {};                  // O[d = dt*32+(r&3)+8*(r>>2)+4h][q=l31]
    float m_run = -60.f, l_run = 0.f;

    f16x8 kr[16], vr[16];
    f32x4 bb[4];

    const int tb = g * 64;             // this wave's tiles [tb, tb+64)

    auto LOADK = [&](int t) {
        const _Float16* p = kTb + (size_t)t * 8192 + h * 256 + l31 * 8;
#pragma unroll
        for (int s = 0; s < 16; ++s)
            kr[s] = *reinterpret_cast<const f16x8*>(p + s * 512);
    };
    auto LOADV = [&](int t) {
        const _Float16* p = vTb + (size_t)t * 8192 + h * 256 + l31 * 8;
#pragma unroll
        for (int i = 0; i < 16; ++i)
            vr[i] = *reinterpret_cast<const f16x8*>(p + i * 512);
    };
    auto LOADB = [&](int t) {
        const float* p = mfb + t * 32 + 4 * h;
#pragma unroll
        for (int gg = 0; gg < 4; ++gg)
            bb[gg] = *reinterpret_cast<const f32x4*>(p + gg * 8);
    };

    LOADK(tb); LOADV(tb); LOADB(tb);

#pragma unroll 1
    for (int t = 0; t < NT; ++t) {
        const int tn = (t + 1 < NT) ? (tb + t + 1) : tb;

        // ---- QK: S[key][q=l31], two 8-deep MFMA chains ----
        f32x16 sA = {}, sB = {};
#pragma unroll
        for (int s = 0; s < 8; ++s) {
            sA = MFMA32(kr[2 * s],     qf[2 * s],     sA);
            sB = MFMA32(kr[2 * s + 1], qf[2 * s + 1], sB);
        }
        LOADK(tn);                       // K(t) dead; prefetch next

        float S[16];
#pragma unroll
        for (int r = 0; r < 16; ++r)
            S[r] = sA[r] + sB[r] + bb[r >> 2][r & 3];
        LOADB(tn);

        // ---- row max: in-register tree + 1 cross-half shuffle ----
        float a0 = fmaxf(S[0], S[1]),   a1 = fmaxf(S[2], S[3]);
        float a2 = fmaxf(S[4], S[5]),   a3 = fmaxf(S[6], S[7]);
        float a4 = fmaxf(S[8], S[9]),   a5 = fmaxf(S[10], S[11]);
        float a6 = fmaxf(S[12], S[13]), a7 = fmaxf(S[14], S[15]);
        float tm = fmaxf(fmaxf(fmaxf(a0, a1), fmaxf(a2, a3)),
                         fmaxf(fmaxf(a4, a5), fmaxf(a6, a7)));
        tm = fmaxf(tm, __shfl_xor(tm, 32, 64));

        if (__any(tm > m_run + 8.f)) {             // defer-max
            float mn = fmaxf(m_run, tm);
            float cs = __expf(m_run - mn);
            m_run = mn; l_run *= cs;
#pragma unroll
            for (int dt = 0; dt < 8; ++dt) o[dt] *= cs;
        }

        // ---- exp + row sum ----
        float p[16];
#pragma unroll
        for (int r = 0; r < 16; ++r) p[r] = __expf(S[r] - m_run);
        float s0 = (p[0] + p[1]) + (p[2] + p[3]);
        float s1 = (p[4] + p[5]) + (p[6] + p[7]);
        float s2 = (p[8] + p[9]) + (p[10] + p[11]);
        float s3 = (p[12] + p[13]) + (p[14] + p[15]);
        float rs = (s0 + s1) + (s2 + s3);
        rs += __shfl_xor(rs, 32, 64);
        l_run += rs;

        // ---- P -> LDS bounce -> PV B-frags (per-warp, in-wave ordered) ----
#pragma unroll
        for (int gg = 0; gg < 4; ++gg) {
            f16x4 hh = { (_Float16)p[4 * gg], (_Float16)p[4 * gg + 1],
                         (_Float16)p[4 * gg + 2], (_Float16)p[4 * gg + 3] };
            *reinterpret_cast<f16x4*>(pw + l31 * 36 + gg * 8 + 4 * h) = hh;
        }
        f16x8 pf0 = *reinterpret_cast<const f16x8*>(pw + l31 * 36 + h * 8);
        f16x8 pf1 = *reinterpret_cast<const f16x8*>(pw + l31 * 36 + 16 + h * 8);

        // ---- PV: O += V^T P, 8 independent accumulators ----
#pragma unroll
        for (int dt = 0; dt < 8; ++dt) {
            o[dt] = MFMA32(vr[2 * dt],     pf0, o[dt]);
            o[dt] = MFMA32(vr[2 * dt + 1], pf1, o[dt]);
        }
        LOADV(tn);                       // V(t) dead; prefetch next
    }

    // ---- epilogue: 2-way split-K merge (R12 structure, scalar m/l) ----
    __syncthreads();
    if (h == 0) { mex[w * 32 + l31] = m_run; lex[w * 32 + l31] = l_run; }
    __syncthreads();

    {
        float mA2 = mex[(qw * 2 + 0) * 32 + l31];
        float mB2 = mex[(qw * 2 + 1) * 32 + l31];
        float mst = fmaxf(mA2, mB2);
        float osc = __expf(m_run - mst);
        float* oq = oexf + qw * (32 * 258);
        if (g == 1) {
#pragma unroll
            for (int dt = 0; dt < 8; ++dt)
#pragma unroll
                for (int r = 0; r < 16; ++r) {
                    int d = dt * 32 + (r & 3) + 8 * (r >> 2) + 4 * h;
                    oq[l31 * 258 + d] = o[dt][r] * osc;
                }
        }
        __syncthreads();
        if (g == 0) {
#pragma unroll
            for (int dt = 0; dt < 8; ++dt)
#pragma unroll
                for (int r = 0; r < 16; ++r) {
                    int d = dt * 32 + (r & 3) + 8 * (r >> 2) + 4 * h;
                    oq[l31 * 258 + d] += o[dt][r] * osc;
                }
        }
        __syncthreads();
    }

    // readout: q = tid>>2 in [0,64), dseg = (tid&3)*64
    {
        const int q = tid >> 2, ds0 = (tid & 3) * 64;
        const int qws = q >> 5, ql = q & 31;
        float mA2 = mex[(qws * 2 + 0) * 32 + ql];
        float mB2 = mex[(qws * 2 + 1) * 32 + ql];
        float ms  = fmaxf(mA2, mB2);
        float lt  = lex[(qws * 2 + 0) * 32 + ql] * __expf(mA2 - ms)
                  + lex[(qws * 2 + 1) * 32 + ql] * __expf(mB2 - ms);
        float inv = 1.f / lt;
        const float* src = oexf + qws * (32 * 258) + ql * 258 + ds0;
        float* dst = outp + base + (size_t)(q0 + q) * Cc + ds0;
#pragma unroll
        for (int i = 0; i < 16; ++i) {
            f32x4 a = *reinterpret_cast<const f32x4*>(src + 4 * i);
            a[0] *= inv; a[1] *= inv; a[2] *= inv; a[3] *= inv;
            *reinterpret_cast<f32x4*>(dst + 4 * i) = a;
        }
    }
}

extern "C" void kernel_launch(void* const* d_in, const int* in_sizes, int n_in,
                              void* d_out, int out_size, void* d_ws, size_t ws_size,
                              hipStream_t stream)
{
    (void)in_sizes; (void)n_in; (void)out_size; (void)ws_size;
    const float* x   = (const float*)d_in[0];
    const int*  mask = (const int*)d_in[1];
    const float* Wk  = (const float*)d_in[2];
    const float* Wq  = (const float*)d_in[3];
    const float* Wv  = (const float*)d_in[4];
    float* out = (float*)d_out;

    _Float16* q  = (_Float16*)d_ws;
    _Float16* k  = q + (size_t)BT * Cc;
    _Float16* vt = k + (size_t)BT * Cc;
    float* maskf = (float*)(vt + (size_t)BT * Cc);

    mask_prep<<<BT / 256, 256, 0, stream>>>(mask, maskf);

    dim3 gA(128, 6), blkA(256);
    size_t ldsA = (size_t)(128 + 128) * 264 * sizeof(_Float16);
    qkv_proj<<<gA, blkA, ldsA, stream>>>(x, Wq, Wk, Wv, q, k, vt);

    dim3 gB(256), blkB(256);
    size_t ldsB = 76288;
    attn_kernel<<<gB, blkB, ldsB, stream>>>(q, k, vt, maskf, out);
}

// Round 14
// 129.490 us; speedup vs baseline: 1.2224x; 1.2224x over previous
//
#include <hip/hip_runtime.h>

// Round 14: R12 base (register-resident, 16x16 dbuf QK ping-pong, no main-loop
// barriers) + KVBLK=32 merged softmax: two 16-key S blocks accumulated, ONE
// softmax/defer/rescale/P-phase per 32 keys (shuffles 16->8 per 32 keys).
// Block 256 = 4 waves (1/SIMD, 512-reg budget) = 2 qw(32q) x 2 g(2048 keys).
//   d_in: 0=x f32, 1=mask i32, 2=Wk, 3=Wq, 4=Wv
// ws (f16): qT [BT/32][8192] | kT [BT/16][4096] | vT [BT/16][4096]
//   qT: [(qh*8+kc)*512 + l4*128 + tok*8 + j]  (x1/16 folded)
//   kT: [kc*512 + ch*128 + key*8 + j]   <-> K[16t+key][kc*32+ch*8+j]
//   vT: [dt*512 + kh*256 + d31*8 + j]   <-> V^T[dt*32+d31][16t+kh*8+j]

typedef __attribute__((ext_vector_type(8)))  _Float16 f16x8;
typedef __attribute__((ext_vector_type(4)))  _Float16 f16x4;
typedef __attribute__((ext_vector_type(4)))  float    f32x4;
typedef __attribute__((ext_vector_type(16))) float    f32x16;

constexpr int Bb = 4;
constexpr int Tt = 4096;
constexpr int Cc = 256;
constexpr int BT = Bb * Tt;

#define MFMA16(a, b, c) __builtin_amdgcn_mfma_f32_16x16x32_f16((a), (b), (c), 0, 0, 0)
#define MFMA32(a, b, c) __builtin_amdgcn_mfma_f32_32x32x16_f16((a), (b), (c), 0, 0, 0)

// ---------------- Kernel A: fused QKV projection (verbatim R12) ----------
__global__ __launch_bounds__(256) void qkv_proj(
    const float* __restrict__ x,
    const float* __restrict__ Wq, const float* __restrict__ Wk,
    const float* __restrict__ Wv,
    _Float16* __restrict__ qo, _Float16* __restrict__ ko,
    _Float16* __restrict__ vto)
{
    extern __shared__ _Float16 sm[];
    _Float16* xs = sm;              // [128][264]
    _Float16* wsm = sm + 128 * 264; // [128][264]

    const int tid = threadIdx.x;
    const int m0  = blockIdx.x * 128;
    const int ny  = blockIdx.y;
    const int mat = ny >> 1;              // 0=q 1=k 2=v
    const int d0  = (ny & 1) * 128;
    const float* W = (mat == 0) ? Wq : (mat == 1 ? Wk : Wv);

#pragma unroll
    for (int i = 0; i < 32; ++i) {
        int flat = i * 256 + tid;
        int r = flat >> 6, c4 = (flat & 63) << 2;
        float4 v = *reinterpret_cast<const float4*>(x + (size_t)(m0 + r) * Cc + c4);
        f16x4 h = { (_Float16)v.x, (_Float16)v.y, (_Float16)v.z, (_Float16)v.w };
        *reinterpret_cast<f16x4*>(xs + r * 264 + c4) = h;
    }
#pragma unroll
    for (int i = 0; i < 32; ++i) {
        int flat = i * 256 + tid;
        int r = flat >> 6, c4 = (flat & 63) << 2;
        float4 v = *reinterpret_cast<const float4*>(W + (size_t)(d0 + r) * Cc + c4);
        f16x4 h = { (_Float16)v.x, (_Float16)v.y, (_Float16)v.z, (_Float16)v.w };
        *reinterpret_cast<f16x4*>(wsm + r * 264 + c4) = h;
    }
    __syncthreads();

    const int w = tid >> 6, lane = tid & 63;
    const int lr = lane & 15, lg = lane >> 4;

    f32x4 acc[2][8] = {};

#pragma unroll
    for (int kc = 0; kc < 8; ++kc) {
        const int c0 = kc * 32 + lg * 8;
        f16x8 xf[2], wf[8];
#pragma unroll
        for (int mb = 0; mb < 2; ++mb)
            xf[mb] = *reinterpret_cast<const f16x8*>(xs + (w * 32 + mb * 16 + lr) * 264 + c0);
#pragma unroll
        for (int db = 0; db < 8; ++db)
            wf[db] = *reinterpret_cast<const f16x8*>(wsm + (db * 16 + lr) * 264 + c0);
        if (mat != 2) {
#pragma unroll
            for (int mb = 0; mb < 2; ++mb)
#pragma unroll
                for (int db = 0; db < 8; ++db)
                    acc[mb][db] = MFMA16(wf[db], xf[mb], acc[mb][db]);   // D[d][tok]
        } else {
#pragma unroll
            for (int mb = 0; mb < 2; ++mb)
#pragma unroll
                for (int db = 0; db < 8; ++db)
                    acc[mb][db] = MFMA16(xf[mb], wf[db], acc[mb][db]);   // D[tok][d]
        }
    }

    if (mat != 2) {
        const float sc = (mat == 0) ? 0.0625f : 1.0f;
        const int jj  = (lg & 1) * 4;
#pragma unroll
        for (int mb = 0; mb < 2; ++mb)
#pragma unroll
            for (int db = 0; db < 8; ++db) {
                int m  = m0 + w * 32 + mb * 16 + lr;
                int c  = d0 + db * 16 + lg * 4;
                int kc = c >> 5;
                int ch = (c >> 3) & 3;
                f32x4 a = acc[mb][db];
                f16x4 h = { (_Float16)(a.x * sc), (_Float16)(a.y * sc),
                            (_Float16)(a.z * sc), (_Float16)(a.w * sc) };
                if (mat == 0) {
                    size_t off = (size_t)(m >> 5) * 8192 + (((m >> 4) & 1) * 8 + kc) * 512
                               + ch * 128 + (m & 15) * 8 + jj;
                    *reinterpret_cast<f16x4*>(qo + off) = h;
                } else {
                    size_t off = (size_t)(m >> 4) * 4096 + kc * 512
                               + ch * 128 + (m & 15) * 8 + jj;
                    *reinterpret_cast<f16x4*>(ko + off) = h;
                }
            }
    } else {
        const int jj = (lg & 1) * 4;
        const int kh = (lg >> 1) & 1;
#pragma unroll
        for (int mb = 0; mb < 2; ++mb)
#pragma unroll
            for (int db = 0; db < 8; ++db) {
                int d = d0 + db * 16 + lr;
                int m = m0 + w * 32 + mb * 16 + lg * 4;
                f32x4 a = acc[mb][db];
                f16x4 h = { (_Float16)a.x, (_Float16)a.y, (_Float16)a.z, (_Float16)a.w };
                size_t off = (size_t)(m >> 4) * 4096 + (d >> 5) * 512
                           + kh * 256 + (d & 31) * 8 + jj;
                *reinterpret_cast<f16x4*>(vto + off) = h;
            }
    }
}

// ---------------- Kernel B: register-resident flash attention ----------------
// LDS (bytes): [0,10240) per-warp P [4][32][40] f16 | [10240,10752) mex f32[4][32]
//              [10752,11264) lex | [11264,77312) oex f32[2 qw][32 q][258]
__global__ __launch_bounds__(256, 1) void attn_kernel(
    const _Float16* __restrict__ qb, const _Float16* __restrict__ kb,
    const _Float16* __restrict__ vtb, const int* __restrict__ mask,
    float* __restrict__ outp)
{
    extern __shared__ char smraw[];
    float* mex  = (float*)(smraw + 10240);
    float* lex  = (float*)(smraw + 10752);
    float* oexf = (float*)(smraw + 11264);

    const int tid = threadIdx.x, w = tid >> 6, lane = tid & 63;
    const int qw = w >> 1, g = w & 1;
    const int l15 = lane & 15, l4 = lane >> 4;
    const int l31 = lane & 31, l5 = lane >> 5;

    const int bid = blockIdx.x;
    const int b   = (bid & 7) >> 1;                    // batch -> XCD pair
    const int qt  = ((bid >> 3) << 1) | (bid & 1);     // [0,64)
    const int q0  = qt * 64;
    const size_t base = (size_t)b * Tt * Cc;
    const int* maskb = mask + (size_t)b * Tt;
    const _Float16* kTb = kb + base;
    const _Float16* vTb = vtb + base;

    // Q fragments: Q[q0 + qw*32 + qh*16 + l15][kc*32 + l4*8 + j]  (x1/16)
    f16x8 qf[2][8];
    {
        const _Float16* qTb = qb + (size_t)(b * 128 + qt * 2 + qw) * 8192;
#pragma unroll
        for (int qh = 0; qh < 2; ++qh)
#pragma unroll
            for (int kc = 0; kc < 8; ++kc)
                qf[qh][kc] = *reinterpret_cast<const f16x8*>(
                    qTb + (qh * 8 + kc) * 512 + l4 * 128 + l15 * 8);
    }

    _Float16* pw = (_Float16*)smraw + w * 1280;        // [32][40] private bounce

    f32x16 o[8] = {};                  // O^T[d = dt*32+(r&3)+8*(r>>2)+4*l5][q=l31]
    float m0r = -60.f, m1r = -60.f, l0r = 0.f, l1r = 0.f;

    auto LOADK = [&](f16x8 (&kr)[8], int tile) {
        const _Float16* kp = kTb + (size_t)tile * 4096 + l4 * 128 + l15 * 8;
#pragma unroll
        for (int kc = 0; kc < 8; ++kc)
            kr[kc] = *reinterpret_cast<const f16x8*>(kp + kc * 512);
    };
    auto LOADV = [&](f16x8 (&vr)[8], int tile) {
        const _Float16* vp = vTb + (size_t)tile * 4096 + l5 * 256 + l31 * 8;
#pragma unroll
        for (int dt = 0; dt < 8; ++dt)
            vr[dt] = *reinterpret_cast<const f16x8*>(vp + dt * 512);
    };

    // QK for one 16-key tile, mask applied: S^T[key = l4*4 + r][q = qh*16 + l15]
    auto QK = [&](f16x8 (&kr)[8], int4 mc, f32x4& s0, f32x4& s1) {
        s0 = (f32x4){ 0.f, 0.f, 0.f, 0.f };
        s1 = (f32x4){ 0.f, 0.f, 0.f, 0.f };
#pragma unroll
        for (int kc = 0; kc < 8; ++kc) {
            s0 = MFMA16(kr[kc], qf[0][kc], s0);
            s1 = MFMA16(kr[kc], qf[1][kc], s1);
        }
        if (mc.x == 0) { s0[0] = -1e30f; s1[0] = -1e30f; }
        if (mc.y == 0) { s0[1] = -1e30f; s1[1] = -1e30f; }
        if (mc.z == 0) { s0[2] = -1e30f; s1[2] = -1e30f; }
        if (mc.w == 0) { s0[3] = -1e30f; s1[3] = -1e30f; }
    };

    // main loop: 64 super-iters x 32 keys; reg ping-pong; NO barriers
    f16x8 kA[8], kB[8], vA[8], vB[8];
    int4 mA_, mB_;
    const int ktb = g * 128;                 // this wave's tiles [ktb, ktb+128)
    LOADK(kA, ktb);     LOADK(kB, ktb + 1);
    LOADV(vA, ktb);     LOADV(vB, ktb + 1);
    mA_ = *reinterpret_cast<const int4*>(maskb + ktb * 16 + l4 * 4);
    mB_ = *reinterpret_cast<const int4*>(maskb + (ktb + 1) * 16 + l4 * 4);

#pragma unroll 1
    for (int t2 = 0; t2 < 64; ++t2) {
        const int tnA = (t2 < 63) ? (ktb + 2 * t2 + 2) : ktb;   // last: dummy
        const int tnB = (t2 < 63) ? (ktb + 2 * t2 + 3) : ktb;

        f32x4 sa0, sa1, sb0, sb1;
        QK(kA, mA_, sa0, sa1);
        LOADK(kA, tnA);                       // K_A dead; prefetch (gap ~= sm+PV)
        QK(kB, mB_, sb0, sb1);
        LOADK(kB, tnB);
        int4 mA2 = *reinterpret_cast<const int4*>(maskb + tnA * 16 + l4 * 4);
        int4 mB2 = *reinterpret_cast<const int4*>(maskb + tnB * 16 + l4 * 4);

        // ---- merged softmax over 32 keys (per qh) ----
        float t0 = fmaxf(fmaxf(fmaxf(sa0[0], sa0[1]), fmaxf(sa0[2], sa0[3])),
                         fmaxf(fmaxf(sb0[0], sb0[1]), fmaxf(sb0[2], sb0[3])));
        float t1 = fmaxf(fmaxf(fmaxf(sa1[0], sa1[1]), fmaxf(sa1[2], sa1[3])),
                         fmaxf(fmaxf(sb1[0], sb1[1]), fmaxf(sb1[2], sb1[3])));
        t0 = fmaxf(t0, __shfl_xor(t0, 16, 64)); t0 = fmaxf(t0, __shfl_xor(t0, 32, 64));
        t1 = fmaxf(t1, __shfl_xor(t1, 16, 64)); t1 = fmaxf(t1, __shfl_xor(t1, 32, 64));

        if (__any(t0 > m0r + 8.f || t1 > m1r + 8.f)) {     // defer-max
            float mn0 = fmaxf(m0r, t0), mn1 = fmaxf(m1r, t1);
            float c0 = __expf(m0r - mn0), c1 = __expf(m1r - mn1);
            m0r = mn0; m1r = mn1; l0r *= c0; l1r *= c1;
            float cs = (lane & 16) ? c1 : c0;              // o cols: q = l31
#pragma unroll
            for (int dt = 0; dt < 8; ++dt) o[dt] *= cs;
        }

        float rs0 = 0.f, rs1 = 0.f;
#pragma unroll
        for (int r = 0; r < 4; ++r) {
            float p;
            p = __expf(sa0[r] - m0r); sa0[r] = p; rs0 += p;
            p = __expf(sb0[r] - m0r); sb0[r] = p; rs0 += p;
            p = __expf(sa1[r] - m1r); sa1[r] = p; rs1 += p;
            p = __expf(sb1[r] - m1r); sb1[r] = p; rs1 += p;
        }
        rs0 += __shfl_xor(rs0, 16, 64); rs0 += __shfl_xor(rs0, 32, 64);
        rs1 += __shfl_xor(rs1, 16, 64); rs1 += __shfl_xor(rs1, 32, 64);
        l0r += rs0; l1r += rs1;

        // ---- P -> pw[q][32keys] f16; reread as PV B-frags ----
        {
            f16x4 h;
            h = (f16x4){ (_Float16)sa0[0], (_Float16)sa0[1], (_Float16)sa0[2], (_Float16)sa0[3] };
            *reinterpret_cast<f16x4*>(pw + l15 * 40 + l4 * 4) = h;
            h = (f16x4){ (_Float16)sb0[0], (_Float16)sb0[1], (_Float16)sb0[2], (_Float16)sb0[3] };
            *reinterpret_cast<f16x4*>(pw + l15 * 40 + 16 + l4 * 4) = h;
            h = (f16x4){ (_Float16)sa1[0], (_Float16)sa1[1], (_Float16)sa1[2], (_Float16)sa1[3] };
            *reinterpret_cast<f16x4*>(pw + (16 + l15) * 40 + l4 * 4) = h;
            h = (f16x4){ (_Float16)sb1[0], (_Float16)sb1[1], (_Float16)sb1[2], (_Float16)sb1[3] };
            *reinterpret_cast<f16x4*>(pw + (16 + l15) * 40 + 16 + l4 * 4) = h;
        }
        f16x8 pf0 = *reinterpret_cast<const f16x8*>(pw + l31 * 40 + l5 * 8);
        f16x8 pf1 = *reinterpret_cast<const f16x8*>(pw + l31 * 40 + 16 + l5 * 8);

        // ---- PV over both 16-key tiles ----
#pragma unroll
        for (int dt = 0; dt < 8; ++dt) {
            o[dt] = MFMA32(vA[dt], pf0, o[dt]);
            o[dt] = MFMA32(vB[dt], pf1, o[dt]);
        }
        LOADV(vA, tnA);                       // V dead; prefetch (gap ~= full iter)
        LOADV(vB, tnB);
        mA_ = mA2; mB_ = mB2;
    }

    // ---- epilogue: 2-way split-K merge (verbatim R12) ----
    __syncthreads();
    if (l4 == 0) {
        mex[w * 32 + l15]      = m0r;  mex[w * 32 + 16 + l15] = m1r;
        lex[w * 32 + l15]      = l0r;  lex[w * 32 + 16 + l15] = l1r;
    }
    __syncthreads();

    {
        float mq  = (lane & 16) ? m1r : m0r;
        float mA2 = mex[(qw * 2 + 0) * 32 + l31];
        float mB2 = mex[(qw * 2 + 1) * 32 + l31];
        float mst = fmaxf(mA2, mB2);
        float osc = __expf(mq - mst);
        float* oq = oexf + qw * (32 * 258);
        if (g == 1) {
#pragma unroll
            for (int dt = 0; dt < 8; ++dt)
#pragma unroll
                for (int r = 0; r < 16; ++r) {
                    int d = dt * 32 + (r & 3) + 8 * (r >> 2) + 4 * l5;
                    oq[l31 * 258 + d] = o[dt][r] * osc;
                }
        }
        __syncthreads();
        if (g == 0) {
#pragma unroll
            for (int dt = 0; dt < 8; ++dt)
#pragma unroll
                for (int r = 0; r < 16; ++r) {
                    int d = dt * 32 + (r & 3) + 8 * (r >> 2) + 4 * l5;
                    oq[l31 * 258 + d] += o[dt][r] * osc;
                }
        }
        __syncthreads();
    }

    // readout: q = tid>>2 in [0,64), dseg = (tid&3)*64
    {
        const int q = tid >> 2, ds0 = (tid & 3) * 64;
        const int qws = q >> 5, ql = q & 31;
        float mA2 = mex[(qws * 2 + 0) * 32 + ql];
        float mB2 = mex[(qws * 2 + 1) * 32 + ql];
        float ms  = fmaxf(mA2, mB2);
        float lt  = lex[(qws * 2 + 0) * 32 + ql] * __expf(mA2 - ms)
                  + lex[(qws * 2 + 1) * 32 + ql] * __expf(mB2 - ms);
        float inv = 1.f / lt;
        const float* src = oexf + qws * (32 * 258) + ql * 258 + ds0;
        float* dst = outp + base + (size_t)(q0 + q) * Cc + ds0;
#pragma unroll
        for (int i = 0; i < 16; ++i) {
            f32x4 a = *reinterpret_cast<const f32x4*>(src + 4 * i);
            a[0] *= inv; a[1] *= inv; a[2] *= inv; a[3] *= inv;
            *reinterpret_cast<f32x4*>(dst + 4 * i) = a;
        }
    }
}

extern "C" void kernel_launch(void* const* d_in, const int* in_sizes, int n_in,
                              void* d_out, int out_size, void* d_ws, size_t ws_size,
                              hipStream_t stream)
{
    (void)in_sizes; (void)n_in; (void)out_size; (void)ws_size;
    const float* x   = (const float*)d_in[0];
    const int*  mask = (const int*)d_in[1];
    const float* Wk  = (const float*)d_in[2];
    const float* Wq  = (const float*)d_in[3];
    const float* Wv  = (const float*)d_in[4];
    float* out = (float*)d_out;

    _Float16* q  = (_Float16*)d_ws;
    _Float16* k  = q + (size_t)BT * Cc;
    _Float16* vt = k + (size_t)BT * Cc;

    dim3 gA(128, 6), blkA(256);
    size_t ldsA = (size_t)(128 + 128) * 264 * sizeof(_Float16);
    qkv_proj<<<gA, blkA, ldsA, stream>>>(x, Wq, Wk, Wv, q, k, vt);

    dim3 gB(256), blkB(256);
    size_t ldsB = 77312;
    attn_kernel<<<gB, blkB, ldsB, stream>>>(q, k, vt, mask, out);
}